// Round 8
// baseline (275.154 us; speedup 1.0000x reference)
//
#include <hip/hip_runtime.h>

#define BTOT 1048576
#define D 17
#define H 8
#define OUT 6
#define E 4
#define G1 64
#define G2 32
#define CHUNKS 2
#define XSTR 20   // sxp row stride (fp32): 17 data + 3 zeros; 80B rows, b128-aligned
#define GTHR 5.0e-3f

typedef float f32x4 __attribute__((ext_vector_type(4)));
typedef float f32x2 __attribute__((ext_vector_type(2)));
typedef short s16x8 __attribute__((ext_vector_type(8)));
typedef unsigned int uint;

union U4S8 { uint u[4]; s16x8 s; };

// round fp32 bits to bf16 (RNE), return fp32 bit pattern (low 16 zeroed)
__device__ __forceinline__ uint bfr(uint u) {
    return (u + 0x7fffu + ((u >> 16) & 1u)) & 0xffff0000u;
}

// RNE 2-way weight split of a pair -> packed bf16x2 words; v ~= h + l, err <= 2^-18|v|
__device__ __forceinline__ void wsplit2(float a, float b, uint &hp, uint &lp) {
    uint ha = bfr(__float_as_uint(a));
    uint hb = bfr(__float_as_uint(b));
    float ra = a - __uint_as_float(ha);
    float rb = b - __uint_as_float(hb);
    hp = (ha >> 16) | (hb & 0xffff0000u);
    lp = (bfr(__float_as_uint(ra)) >> 16) | (bfr(__float_as_uint(rb)) & 0xffff0000u);
}

// trunc 2-way activation split of 8 values (ascending k), perm-packed:
// v = h + m + delta, |m| <= 2^-8|v| (one-sided), |delta| <= 2^-16|v|
__device__ __forceinline__ void split8t2(const float* p, s16x8 &fh, s16x8 &fm) {
    U4S8 Hh, Mm;
    #pragma unroll
    for (int i = 0; i < 4; ++i) {
        float a = p[2 * i], b = p[2 * i + 1];
        uint ua = __float_as_uint(a), ub = __float_as_uint(b);
        Hh.u[i] = __builtin_amdgcn_perm(ub, ua, 0x07060302u);   // [a.hi16 | b.hi16<<16]
        float ra = a - __uint_as_float(ua & 0xffff0000u);       // exact
        float rb = b - __uint_as_float(ub & 0xffff0000u);
        Mm.u[i] = __builtin_amdgcn_perm(__float_as_uint(rb), __float_as_uint(ra), 0x07060302u);
    }
    fh = Hh.s; fm = Mm.s;
}

// 3-term MFMA product: D += (ah+am)*(bh+bl), ascending magnitude order.
// dropped: am*bl (2^-17), act delta (2^-16), wt eps (2^-18) -> logit err ~2e-5 typ
#define MM3(dacc, ah, am, bh, bl)                                                \
    dacc = __builtin_amdgcn_mfma_f32_16x16x32_bf16(am, bh, dacc, 0, 0, 0);       \
    dacc = __builtin_amdgcn_mfma_f32_16x16x32_bf16(ah, bl, dacc, 0, 0, 0);       \
    dacc = __builtin_amdgcn_mfma_f32_16x16x32_bf16(ah, bh, dacc, 0, 0, 0);

__global__ __launch_bounds__(256, 2) void hybrid_ruc_kernel(
    const float* __restrict__ x,
    const float* __restrict__ eW1, const float* __restrict__ eb1,
    const float* __restrict__ eW2, const float* __restrict__ eb2,
    const float* __restrict__ eW3, const float* __restrict__ eb3,
    const float* __restrict__ gW1, const float* __restrict__ gb1,
    const float* __restrict__ gW2, const float* __restrict__ gb2,
    const float* __restrict__ gW3, const float* __restrict__ gb3,
    float* __restrict__ out)
{
    // ---- LDS: 16384 + 20544 = 36928 B -> 4 blocks/CU ----
    __shared__ __align__(16) float sscr[4][1024];         // per-wave scratch
    __shared__ __align__(16) float sxp[256 * XSTR + 16];  // x fp32 padded + zero tail

    const int tid = threadIdx.x;
    const int wv  = tid >> 6;
    const int ln  = tid & 63;
    const int g   = ln >> 4;   // k-block group for MFMA fragments
    const int nn  = ln & 15;   // row (A) / col (B,D) within 16-tile
    float* scr = sscr[wv];

    // ---- one-time: zero pads (k=17..19 each row) + tail ----
    sxp[tid * XSTR + 17] = 0.0f;
    sxp[tid * XSTR + 18] = 0.0f;
    sxp[tid * XSTR + 19] = 0.0f;
    if (tid < 16) sxp[256 * XSTR + tid] = 0.0f;

    // ---- hoist gating biases + B-fragments from GLOBAL into registers ----
    float cb1[4], cb2[2], cb3;
    #pragma unroll
    for (int ct = 0; ct < 4; ++ct) cb1[ct] = gb1[ct * 16 + nn];
    cb2[0] = gb2[nn]; cb2[1] = gb2[16 + nn];
    cb3 = (nn < 4) ? gb3[nn] : 0.0f;

    s16x8 B1h[4], B1l[4];          // k = g*8..+7; k>=17 zero; g==3 all-zero
    #pragma unroll
    for (int ct = 0; ct < 4; ++ct) {
        U4S8 Hh, Ll;
        #pragma unroll
        for (int j2 = 0; j2 < 4; ++j2) {
            const int k0 = g * 8 + 2 * j2, n = ct * 16 + nn;
            const float a = (k0 < D)     ? gW1[k0 * G1 + n]       : 0.0f;
            const float b = (k0 + 1 < D) ? gW1[(k0 + 1) * G1 + n] : 0.0f;
            wsplit2(a, b, Hh.u[j2], Ll.u[j2]);
        }
        B1h[ct] = Hh.s; B1l[ct] = Ll.s;
    }
    s16x8 B2h[2][2], B2l[2][2];    // k = kt*32 + g*8..+7 (all valid)
    #pragma unroll
    for (int ct = 0; ct < 2; ++ct)
        #pragma unroll
        for (int kt = 0; kt < 2; ++kt) {
            U4S8 Hh, Ll;
            #pragma unroll
            for (int j2 = 0; j2 < 4; ++j2) {
                const int k0 = kt * 32 + g * 8 + 2 * j2, n = ct * 16 + nn;
                wsplit2(gW2[k0 * G2 + n], gW2[(k0 + 1) * G2 + n], Hh.u[j2], Ll.u[j2]);
            }
            B2h[ct][kt] = Hh.s; B2l[ct][kt] = Ll.s;
        }
    s16x8 B3h, B3l;                // k = g*8..+7; cols nn>=4 zero
    {
        U4S8 Hh, Ll;
        #pragma unroll
        for (int j2 = 0; j2 < 4; ++j2) {
            const int k0 = g * 8 + 2 * j2;
            const float a = (nn < 4) ? gW3[k0 * E + nn]       : 0.0f;
            const float b = (nn < 4) ? gW3[(k0 + 1) * E + nn] : 0.0f;
            wsplit2(a, b, Hh.u[j2], Ll.u[j2]);
        }
        B3h = Hh.s; B3l = Ll.s;
    }

    // precompute staging div once: tid = 17*q0 + r0
    const int q0 = tid / 17;
    const int r0 = tid - q0 * 17;

    // ======== chunk loop ========
    #pragma unroll 1
    for (int c = 0; c < CHUNKS; ++c) {
        const long long cbase = ((long long)blockIdx.x * CHUNKS + c) * 256;
        if (c) __syncthreads();                 // prev chunk fully consumed

        // stage x chunk: coalesced global, strided LDS (256 ≡ 1 mod 17)
        #pragma unroll
        for (int j = 0; j < D; ++j) {
            const int rj = r0 + j;
            const int cy = (rj >= 17) ? 1 : 0;
            const int k  = rj - (cy ? 17 : 0);
            const int s  = 15 * j + q0 + cy;
            sxp[s * XSTR + k] = x[cbase * D + tid + j * 256];
        }
        __syncthreads();                        // staged (+ pads on c==0) visible

        // ---- gating via MFMA (per-wave: 4 row-tiles of 16 samples) ----
        f32x4 Lg[4];
        #pragma unroll
        for (int rt = 0; rt < 4; ++rt) {
            const int srow = wv * 64 + rt * 16 + nn;
            // A1: 8 fp32, b128-aligned; g==3 clamps to row start (zero weights)
            float xv[8];
            const int xb = srow * XSTR + ((g == 3) ? 0 : g * 8);
            *(f32x4*)&xv[0] = *(const f32x4*)(&sxp[xb]);
            *(f32x4*)&xv[4] = *(const f32x4*)(&sxp[xb + 4]);
            s16x8 a1h, a1m; split8t2(xv, a1h, a1m);

            // L1: 17->64, 4 col-tiles
            #pragma unroll
            for (int ct = 0; ct < 4; ++ct) {
                f32x4 d = {cb1[ct], cb1[ct], cb1[ct], cb1[ct]};
                MM3(d, a1h, a1m, B1h[ct], B1l[ct]);
                #pragma unroll
                for (int r = 0; r < 4; ++r) {
                    float hv = fmaxf(d[r], 0.0f);
                    int s = g * 4 + r, n = ct * 16 + nn;
                    scr[s * 64 + (((n >> 2) ^ (s & 15)) << 2) + (n & 3)] = hv;
                }
            }

            // A2 frags from h1
            s16x8 a2h[2], a2m[2];
            #pragma unroll
            for (int kt = 0; kt < 2; ++kt) {
                int kb0 = kt * 8 + g * 2;
                float hv8[8];
                *(f32x4*)&hv8[0] = *(const f32x4*)(&scr[nn * 64 + ((kb0 ^ nn) << 2)]);
                *(f32x4*)&hv8[4] = *(const f32x4*)(&scr[nn * 64 + (((kb0 + 1) ^ nn) << 2)]);
                split8t2(hv8, a2h[kt], a2m[kt]);
            }

            // L2: 64->32
            #pragma unroll
            for (int ct = 0; ct < 2; ++ct) {
                f32x4 d = {cb2[ct], cb2[ct], cb2[ct], cb2[ct]};
                #pragma unroll
                for (int kt = 0; kt < 2; ++kt) {
                    MM3(d, a2h[kt], a2m[kt], B2h[ct][kt], B2l[ct][kt]);
                }
                #pragma unroll
                for (int r = 0; r < 4; ++r) {
                    float hv = fmaxf(d[r], 0.0f);
                    int s = g * 4 + r, n = ct * 16 + nn;
                    scr[s * 32 + (((n >> 2) ^ (s & 7)) << 2) + (n & 3)] = hv;
                }
            }

            // A3 frags from h2
            float h28[8];
            *(f32x4*)&h28[0] = *(const f32x4*)(&scr[nn * 32 + (((2 * g) ^ (nn & 7)) << 2)]);
            *(f32x4*)&h28[4] = *(const f32x4*)(&scr[nn * 32 + (((2 * g + 1) ^ (nn & 7)) << 2)]);
            s16x8 a3h, a3m; split8t2(h28, a3h, a3m);

            // L3: 32->4
            f32x4 d3 = {cb3, cb3, cb3, cb3};
            MM3(d3, a3h, a3m, B3h, B3l);
            Lg[rt] = d3;
        }

        // ---- redistribute logits: D-layout -> one sample per lane ----
        if (nn < 4) {
            #pragma unroll
            for (int rt = 0; rt < 4; ++rt)
                #pragma unroll
                for (int r = 0; r < 4; ++r)
                    scr[(rt * 16 + g * 4 + r) * 4 + nn] = Lg[rt][r];
        }
        f32x4 lgv = *(const f32x4*)(&scr[ln * 4]);

        // ---- argmax (first-max-wins) + top-2 gap ----
        int sel = 0;
        {
            float b = lgv.x;
            if (lgv.y > b) { b = lgv.y; sel = 1; }
            if (lgv.z > b) { b = lgv.z; sel = 2; }
            if (lgv.w > b) { b = lgv.w; sel = 3; }
        }
        float mx01 = fmaxf(lgv.x, lgv.y), mn01 = fminf(lgv.x, lgv.y);
        float mx23 = fmaxf(lgv.z, lgv.w), mn23 = fminf(lgv.z, lgv.w);
        float best   = fmaxf(mx01, mx23);
        float second = fmaxf(fminf(mx01, mx23), (mx01 >= mx23) ? mn01 : mn23);

        // ---- rare exact-fp32 cooperative fallback for near-tie routing ----
        unsigned long long fmask = __ballot(best - second < GTHR);
        if (fmask) {
            do {
                int sl = (int)__builtin_ctzll(fmask);
                fmask &= (fmask - 1);
                const int fr = wv * 64 + sl;
                float h1j = gb1[ln];
                #pragma unroll 1
                for (int i = 0; i < D; ++i)
                    h1j = __builtin_fmaf(sxp[fr * XSTR + i], gW1[i * G1 + ln], h1j);
                scr[ln] = fmaxf(h1j, 0.0f);
                int j2 = ln & 31;
                float h2j = gb2[j2];
                #pragma unroll 4
                for (int c2 = 0; c2 < G1; ++c2)
                    h2j = __builtin_fmaf(scr[c2], gW2[c2 * G2 + j2], h2j);
                scr[64 + j2] = fmaxf(h2j, 0.0f);
                int e = ln & 3;
                float lge = gb3[e];
                #pragma unroll 4
                for (int jj = 0; jj < G2; ++jj)
                    lge = __builtin_fmaf(scr[64 + jj], gW3[jj * E + e], lge);
                float l0 = __shfl(lge, 0), l1 = __shfl(lge, 1);
                float l2 = __shfl(lge, 2), l3 = __shfl(lge, 3);
                int s2 = 0; float bb = l0;
                if (l1 > bb) { bb = l1; s2 = 1; }
                if (l2 > bb) { bb = l2; s2 = 2; }
                if (l3 > bb) { bb = l3; s2 = 3; }
                if (ln == sl) sel = s2;
            } while (fmask);
        }

        // ---- selected expert: weights gathered from GLOBAL (L1-resident) ----
        float xr[D];
        {
            const float* xrow = &sxp[tid * XSTR];
            f32x4 x0 = *(const f32x4*)(xrow);
            f32x4 x1 = *(const f32x4*)(xrow + 4);
            f32x4 x2 = *(const f32x4*)(xrow + 8);
            f32x4 x3 = *(const f32x4*)(xrow + 12);
            xr[0]=x0.x; xr[1]=x0.y; xr[2]=x0.z; xr[3]=x0.w;
            xr[4]=x1.x; xr[5]=x1.y; xr[6]=x1.z; xr[7]=x1.w;
            xr[8]=x2.x; xr[9]=x2.y; xr[10]=x2.z; xr[11]=x2.w;
            xr[12]=x3.x; xr[13]=x3.y; xr[14]=x3.z; xr[15]=x3.w;
            xr[16]=xrow[16];
        }
        const float* w1g = eW1 + sel * (D * H);   // 544B stride: 16B-aligned
        const float* w2g = eW2 + sel * (H * H);
        const float* w3g = eW3 + sel * (H * OUT);

        float t1[H];
        {
            const float* bg = eb1 + sel * H;
            f32x4 ba = *(const f32x4*)(bg);
            f32x4 bb = *(const f32x4*)(bg + 4);
            t1[0]=ba.x; t1[1]=ba.y; t1[2]=ba.z; t1[3]=ba.w;
            t1[4]=bb.x; t1[5]=bb.y; t1[6]=bb.z; t1[7]=bb.w;
        }
        #pragma unroll
        for (int i = 0; i < D; ++i) {
            const float xi = xr[i];
            f32x4 wa = *(const f32x4*)(w1g + i * 8);
            f32x4 wb = *(const f32x4*)(w1g + i * 8 + 4);
            t1[0] = __builtin_fmaf(xi, wa.x, t1[0]);
            t1[1] = __builtin_fmaf(xi, wa.y, t1[1]);
            t1[2] = __builtin_fmaf(xi, wa.z, t1[2]);
            t1[3] = __builtin_fmaf(xi, wa.w, t1[3]);
            t1[4] = __builtin_fmaf(xi, wb.x, t1[4]);
            t1[5] = __builtin_fmaf(xi, wb.y, t1[5]);
            t1[6] = __builtin_fmaf(xi, wb.z, t1[6]);
            t1[7] = __builtin_fmaf(xi, wb.w, t1[7]);
        }
        float t2[H];
        {
            const float* bg = eb2 + sel * H;
            f32x4 ba = *(const f32x4*)(bg);
            f32x4 bb = *(const f32x4*)(bg + 4);
            t2[0]=ba.x; t2[1]=ba.y; t2[2]=ba.z; t2[3]=ba.w;
            t2[4]=bb.x; t2[5]=bb.y; t2[6]=bb.z; t2[7]=bb.w;
        }
        #pragma unroll
        for (int k = 0; k < H; ++k) {
            const float tv = fmaxf(t1[k], 0.0f);
            f32x4 wa = *(const f32x4*)(w2g + k * 8);
            f32x4 wb = *(const f32x4*)(w2g + k * 8 + 4);
            t2[0] = __builtin_fmaf(tv, wa.x, t2[0]);
            t2[1] = __builtin_fmaf(tv, wa.y, t2[1]);
            t2[2] = __builtin_fmaf(tv, wa.z, t2[2]);
            t2[3] = __builtin_fmaf(tv, wa.w, t2[3]);
            t2[4] = __builtin_fmaf(tv, wb.x, t2[4]);
            t2[5] = __builtin_fmaf(tv, wb.y, t2[5]);
            t2[6] = __builtin_fmaf(tv, wb.z, t2[6]);
            t2[7] = __builtin_fmaf(tv, wb.w, t2[7]);
        }
        float pred[OUT];
        {
            const float* bg = eb3 + sel * OUT;    // 24B stride: 8B-aligned
            f32x2 b0 = *(const f32x2*)(bg);
            f32x2 b1 = *(const f32x2*)(bg + 2);
            f32x2 b2 = *(const f32x2*)(bg + 4);
            pred[0]=b0.x; pred[1]=b0.y; pred[2]=b1.x; pred[3]=b1.y;
            pred[4]=b2.x; pred[5]=b2.y;
        }
        #pragma unroll
        for (int j = 0; j < 4; ++j) {             // rows 2j, 2j+1 (12 floats, 16B-aligned)
            const float tv0 = fmaxf(t2[2 * j],     0.0f);
            const float tv1 = fmaxf(t2[2 * j + 1], 0.0f);
            f32x4 wa = *(const f32x4*)(w3g + j * 12);
            f32x4 wb = *(const f32x4*)(w3g + j * 12 + 4);
            f32x4 wc = *(const f32x4*)(w3g + j * 12 + 8);
            pred[0] = __builtin_fmaf(tv0, wa.x, pred[0]);
            pred[1] = __builtin_fmaf(tv0, wa.y, pred[1]);
            pred[2] = __builtin_fmaf(tv0, wa.z, pred[2]);
            pred[3] = __builtin_fmaf(tv0, wa.w, pred[3]);
            pred[4] = __builtin_fmaf(tv0, wb.x, pred[4]);
            pred[5] = __builtin_fmaf(tv0, wb.y, pred[5]);
            pred[0] = __builtin_fmaf(tv1, wb.z, pred[0]);
            pred[1] = __builtin_fmaf(tv1, wb.w, pred[1]);
            pred[2] = __builtin_fmaf(tv1, wc.x, pred[2]);
            pred[3] = __builtin_fmaf(tv1, wc.y, pred[3]);
            pred[4] = __builtin_fmaf(tv1, wc.z, pred[4]);
            pred[5] = __builtin_fmaf(tv1, wc.w, pred[5]);
        }

        // ---- stores ----
        const long long b = cbase + tid;
        f32x2 p0 = {pred[0], pred[1]};
        f32x2 p1 = {pred[2], pred[3]};
        f32x2 p2 = {pred[4], pred[5]};
        *(f32x2*)(out + b * 6)     = p0;
        *(f32x2*)(out + b * 6 + 2) = p1;
        *(f32x2*)(out + b * 6 + 4) = p2;
        float* lout = out + (long long)BTOT * OUT;
        *(f32x4*)(lout + b * 4) = lgv;
    }
}

extern "C" void kernel_launch(void* const* d_in, const int* in_sizes, int n_in,
                              void* d_out, int out_size, void* d_ws, size_t ws_size,
                              hipStream_t stream) {
    const float* x   = (const float*)d_in[0];
    const float* eW1 = (const float*)d_in[1];
    const float* eb1 = (const float*)d_in[2];
    const float* eW2 = (const float*)d_in[3];
    const float* eb2 = (const float*)d_in[4];
    const float* eW3 = (const float*)d_in[5];
    const float* eb3 = (const float*)d_in[6];
    const float* gW1 = (const float*)d_in[7];
    const float* gb1 = (const float*)d_in[8];
    const float* gW2 = (const float*)d_in[9];
    const float* gb2 = (const float*)d_in[10];
    const float* gW3 = (const float*)d_in[11];
    const float* gb3 = (const float*)d_in[12];
    float* out = (float*)d_out;

    dim3 grid(BTOT / (256 * CHUNKS)), block(256);
    hipLaunchKernelGGL(hybrid_ruc_kernel, grid, block, 0, stream,
                       x, eW1, eb1, eW2, eb2, eW3, eb3,
                       gW1, gb1, gW2, gb2, gW3, gb3, out);
}

// Round 9
// 252.602 us; speedup vs baseline: 1.0893x; 1.0893x over previous
//
#include <hip/hip_runtime.h>

#define BTOT 1048576
#define D 17
#define H 8
#define OUT 6
#define E 4
#define G1 64
#define G2 32
#define GTHR 1.0e-2f
#define NWPK 1664   // packed gating weight words: 576 (W1) + 1024 (W2) + 64 (W3)

typedef float f32x4 __attribute__((ext_vector_type(4)));
typedef float f32x2 __attribute__((ext_vector_type(2)));
typedef _Float16 h16x2 __attribute__((ext_vector_type(2)));
typedef unsigned int uint;

#if defined(__has_builtin)
# if __has_builtin(__builtin_amdgcn_fdot2)
#  define HAVE_FDOT2 1
# endif
#endif

// packed gating weights, f16 RNE pairs (written by pack_kernel, stream-ordered)
__device__ __align__(16) uint g_wpack[NWPK];

union UH { uint u; h16x2 h; };

// acc += a.x*w.x + a.y*w.y  (v_dot2_f32_f16: 2 MACs/inst, fp32 accumulate;
// w is wave-uniform -> SGPR operand)
__device__ __forceinline__ float dot2f(float acc, h16x2 a, uint w) {
    UH c; c.u = w;
#ifdef HAVE_FDOT2
    return __builtin_amdgcn_fdot2(a, c.h, acc, false);
#else
    asm("v_dot2_f32_f16 %0, %1, %2, %0" : "+v"(acc) : "v"(a), "s"(w));
    return acc;
#endif
}

// ---- pre-kernel: pack gating weights into f16 pairs (RNE), one-time ----
// layout: [i2*64 + n] i2<9 (W1, k-pairs; k=17 padded 0) |
//         [576 + c2*32 + j] c2<32 (W2) | [1600 + j2*4 + e] j2<16 (W3)
__global__ __launch_bounds__(256) void pack_kernel(
    const float* __restrict__ gW1, const float* __restrict__ gW2,
    const float* __restrict__ gW3)
{
    for (int idx = threadIdx.x; idx < NWPK; idx += 256) {
        float a, b;
        if (idx < 576) {
            int i2 = idx >> 6, n = idx & 63;
            a = gW1[(2 * i2) * G1 + n];
            b = (2 * i2 + 1 < D) ? gW1[(2 * i2 + 1) * G1 + n] : 0.0f;
        } else if (idx < 1600) {
            int r = idx - 576, c2 = r >> 5, j = r & 31;
            a = gW2[(2 * c2) * G2 + j];
            b = gW2[(2 * c2 + 1) * G2 + j];
        } else {
            int r = idx - 1600, j2 = r >> 2, e = r & 3;
            a = gW3[(2 * j2) * E + e];
            b = gW3[(2 * j2 + 1) * E + e];
        }
        UH p; p.h = h16x2{(_Float16)a, (_Float16)b};   // RNE converts
        g_wpack[idx] = p.u;
    }
}

#define WSTR 296  // expert LDS stride (dwords): blocks start on bank groups {0,8,16,24}

__global__ __launch_bounds__(256) void hybrid_ruc_kernel(
    const float* __restrict__ x,
    const float* __restrict__ eW1, const float* __restrict__ eb1,
    const float* __restrict__ eW2, const float* __restrict__ eb2,
    const float* __restrict__ eW3, const float* __restrict__ eb3,
    const float* __restrict__ gW1, const float* __restrict__ gb1,
    const float* __restrict__ gW2, const float* __restrict__ gb2,
    const float* __restrict__ gW3, const float* __restrict__ gb3,
    float* __restrict__ out)
{
    // ---- LDS: 17408 + 4736 + 1536 = 23680 B ----
    __shared__ float sx[256 * D];
    __shared__ __align__(16) float swl[E * WSTR];
    __shared__ float sfb[4][96];            // per-wave fallback scratch

    const int tid = threadIdx.x;
    const int wv  = tid >> 6;
    const int ln  = tid & 63;
    const long long bbase = (long long)blockIdx.x * 256;
    const uint* __restrict__ wp = g_wpack;

    // ---- stage this block's x rows into LDS (coalesced, R1 pattern) ----
    #pragma unroll
    for (int k = 0; k < D; ++k) {
        int t = tid + k * 256;
        sx[t] = x[bbase * D + t];
    }
    // ---- stage expert weights into LDS (R1 bank-group layout) ----
    for (int t = tid; t < E * D * H; t += 256) {          // eW1: 544
        swl[(t / 136) * WSTR + (t % 136)] = eW1[t];
    }
    if (tid < E * H * H) {                                 // eW2: 256
        swl[(tid / 64) * WSTR + 144 + (tid % 64)] = eW2[tid];
    }
    if (tid < E * H * OUT) {                               // eW3: 192, rows padded to 8
        int e = tid / 48, r = tid % 48, k = r / 6, o = r % 6;
        swl[e * WSTR + 216 + k * 8 + o] = eW3[tid];
    }
    if (tid < E * H) swl[(tid / 8) * WSTR + 136 + (tid % 8)] = eb1[tid];
    if (tid < E * H) swl[(tid / 8) * WSTR + 208 + (tid % 8)] = eb2[tid];
    if (tid < E * OUT) swl[(tid / 6) * WSTR + 280 + (tid % 6)] = eb3[tid];
    __syncthreads();

    // per-thread x row (stride-17 LDS reads: 2-way bank alias, free)
    float xr[D];
    #pragma unroll
    for (int i = 0; i < D; ++i) xr[i] = sx[tid * D + i];

    // ---- pack x to f16 pairs (RNE) ----
    h16x2 xp[9];
    #pragma unroll
    for (int i2 = 0; i2 < 8; ++i2)
        xp[i2] = h16x2{(_Float16)xr[2 * i2], (_Float16)xr[2 * i2 + 1]};
    xp[8] = h16x2{(_Float16)xr[16], (_Float16)0.0f};

    // ---- gating L1 (17->64), dot2, 4 tiles of 16 ----
    h16x2 hp1[32];
    #pragma unroll
    for (int jt = 0; jt < 4; ++jt) {
        float ha[16];
        #pragma unroll
        for (int c = 0; c < 16; ++c) ha[c] = gb1[jt * 16 + c];
        #pragma unroll
        for (int i2 = 0; i2 < 9; ++i2) {
            #pragma unroll
            for (int c = 0; c < 16; ++c)
                ha[c] = dot2f(ha[c], xp[i2], wp[i2 * 64 + jt * 16 + c]);
        }
        #pragma unroll
        for (int c2 = 0; c2 < 8; ++c2)
            hp1[jt * 8 + c2] = h16x2{(_Float16)fmaxf(ha[2 * c2], 0.0f),
                                     (_Float16)fmaxf(ha[2 * c2 + 1], 0.0f)};
    }

    // ---- gating L2 (64->32), dot2, 2 tiles of 16 ----
    h16x2 hp2[16];
    #pragma unroll
    for (int jt = 0; jt < 2; ++jt) {
        float ja[16];
        #pragma unroll
        for (int j = 0; j < 16; ++j) ja[j] = gb2[jt * 16 + j];
        #pragma unroll
        for (int c2 = 0; c2 < 32; ++c2) {
            #pragma unroll
            for (int j = 0; j < 16; ++j)
                ja[j] = dot2f(ja[j], hp1[c2], wp[576 + c2 * 32 + jt * 16 + j]);
        }
        #pragma unroll
        for (int j2 = 0; j2 < 8; ++j2)
            hp2[jt * 8 + j2] = h16x2{(_Float16)fmaxf(ja[2 * j2], 0.0f),
                                     (_Float16)fmaxf(ja[2 * j2 + 1], 0.0f)};
    }

    // ---- gating L3 (32->4), dot2 ----
    float lg[E];
    #pragma unroll
    for (int e = 0; e < E; ++e) lg[e] = gb3[e];
    #pragma unroll
    for (int j2 = 0; j2 < 16; ++j2) {
        #pragma unroll
        for (int e = 0; e < E; ++e)
            lg[e] = dot2f(lg[e], hp2[j2], wp[1600 + j2 * 4 + e]);
    }

    // ---- argmax (first-max-wins) + top-2 gap ----
    int sel = 0;
    {
        float b = lg[0];
        if (lg[1] > b) { b = lg[1]; sel = 1; }
        if (lg[2] > b) { b = lg[2]; sel = 2; }
        if (lg[3] > b) { b = lg[3]; sel = 3; }
    }
    float mx01 = fmaxf(lg[0], lg[1]), mn01 = fminf(lg[0], lg[1]);
    float mx23 = fmaxf(lg[2], lg[3]), mn23 = fminf(lg[2], lg[3]);
    float best   = fmaxf(mx01, mx23);
    float second = fmaxf(fminf(mx01, mx23), (mx01 >= mx23) ? mn01 : mn23);

    // ---- rare exact-fp32 cooperative fallback for near-tie routing ----
    unsigned long long fmask = __ballot(best - second < GTHR);
    if (fmask) {
        float* fs = sfb[wv];
        do {
            int sl = (int)__builtin_ctzll(fmask);
            fmask &= (fmask - 1);
            const int fr = wv * 64 + sl;           // flagged sample's sx row
            float h1j = gb1[ln];
            #pragma unroll 1
            for (int i = 0; i < D; ++i)
                h1j = __builtin_fmaf(sx[fr * D + i], gW1[i * G1 + ln], h1j);
            fs[ln] = fmaxf(h1j, 0.0f);
            int j2 = ln & 31;
            float h2j = gb2[j2];
            #pragma unroll 4
            for (int c2 = 0; c2 < G1; ++c2)
                h2j = __builtin_fmaf(fs[c2], gW2[c2 * G2 + j2], h2j);
            fs[64 + j2] = fmaxf(h2j, 0.0f);
            int e = ln & 3;
            float lge = gb3[e];
            #pragma unroll 4
            for (int jj = 0; jj < G2; ++jj)
                lge = __builtin_fmaf(fs[64 + jj], gW3[jj * E + e], lge);
            float l0 = __shfl(lge, 0), l1 = __shfl(lge, 1);
            float l2 = __shfl(lge, 2), l3 = __shfl(lge, 3);
            int s2 = 0; float bb = l0;
            if (l1 > bb) { bb = l1; s2 = 1; }
            if (l2 > bb) { bb = l2; s2 = 2; }
            if (l3 > bb) { bb = l3; s2 = 3; }
            if (ln == sl) sel = s2;
        } while (fmask);
    }

    // ---- selected expert only, fp32-exact, weights gathered from LDS (R1) ----
    const float* wl = &swl[sel * WSTR];

    float t1[H];
    {
        f32x4 ba = *(const f32x4*)(wl + 136);
        f32x4 bb = *(const f32x4*)(wl + 140);
        t1[0]=ba.x; t1[1]=ba.y; t1[2]=ba.z; t1[3]=ba.w;
        t1[4]=bb.x; t1[5]=bb.y; t1[6]=bb.z; t1[7]=bb.w;
    }
    #pragma unroll
    for (int i = 0; i < D; ++i) {
        const float xi = xr[i];
        f32x4 wa = *(const f32x4*)(wl + i * 8);
        f32x4 wb = *(const f32x4*)(wl + i * 8 + 4);
        t1[0] = __builtin_fmaf(xi, wa.x, t1[0]);
        t1[1] = __builtin_fmaf(xi, wa.y, t1[1]);
        t1[2] = __builtin_fmaf(xi, wa.z, t1[2]);
        t1[3] = __builtin_fmaf(xi, wa.w, t1[3]);
        t1[4] = __builtin_fmaf(xi, wb.x, t1[4]);
        t1[5] = __builtin_fmaf(xi, wb.y, t1[5]);
        t1[6] = __builtin_fmaf(xi, wb.z, t1[6]);
        t1[7] = __builtin_fmaf(xi, wb.w, t1[7]);
    }
    float t2[H];
    {
        f32x4 ba = *(const f32x4*)(wl + 208);
        f32x4 bb = *(const f32x4*)(wl + 212);
        t2[0]=ba.x; t2[1]=ba.y; t2[2]=ba.z; t2[3]=ba.w;
        t2[4]=bb.x; t2[5]=bb.y; t2[6]=bb.z; t2[7]=bb.w;
    }
    #pragma unroll
    for (int k = 0; k < H; ++k) {
        const float tv = fmaxf(t1[k], 0.0f);
        f32x4 wa = *(const f32x4*)(wl + 144 + k * 8);
        f32x4 wb = *(const f32x4*)(wl + 144 + k * 8 + 4);
        t2[0] = __builtin_fmaf(tv, wa.x, t2[0]);
        t2[1] = __builtin_fmaf(tv, wa.y, t2[1]);
        t2[2] = __builtin_fmaf(tv, wa.z, t2[2]);
        t2[3] = __builtin_fmaf(tv, wa.w, t2[3]);
        t2[4] = __builtin_fmaf(tv, wb.x, t2[4]);
        t2[5] = __builtin_fmaf(tv, wb.y, t2[5]);
        t2[6] = __builtin_fmaf(tv, wb.z, t2[6]);
        t2[7] = __builtin_fmaf(tv, wb.w, t2[7]);
    }
    float pred[OUT];
    {
        f32x4 ba = *(const f32x4*)(wl + 280);
        pred[0]=ba.x; pred[1]=ba.y; pred[2]=ba.z; pred[3]=ba.w;
        pred[4]=wl[284]; pred[5]=wl[285];
    }
    #pragma unroll
    for (int k = 0; k < H; ++k) {
        const float tv = fmaxf(t2[k], 0.0f);
        f32x4 wa = *(const f32x4*)(wl + 216 + k * 8);
        f32x2 wb = *(const f32x2*)(wl + 216 + k * 8 + 4);
        pred[0] = __builtin_fmaf(tv, wa.x, pred[0]);
        pred[1] = __builtin_fmaf(tv, wa.y, pred[1]);
        pred[2] = __builtin_fmaf(tv, wa.z, pred[2]);
        pred[3] = __builtin_fmaf(tv, wa.w, pred[3]);
        pred[4] = __builtin_fmaf(tv, wb.x, pred[4]);
        pred[5] = __builtin_fmaf(tv, wb.y, pred[5]);
    }

    // ---- stores: predictions [B,6] then gating_logits [B,4] ----
    const long long b = bbase + tid;
    f32x2 p0 = {pred[0], pred[1]};
    f32x2 p1 = {pred[2], pred[3]};
    f32x2 p2 = {pred[4], pred[5]};
    *(f32x2*)(out + b * 6)     = p0;
    *(f32x2*)(out + b * 6 + 2) = p1;
    *(f32x2*)(out + b * 6 + 4) = p2;
    float* lout = out + (long long)BTOT * OUT;
    f32x4 lgv = {lg[0], lg[1], lg[2], lg[3]};
    *(f32x4*)(lout + b * 4) = lgv;
}

extern "C" void kernel_launch(void* const* d_in, const int* in_sizes, int n_in,
                              void* d_out, int out_size, void* d_ws, size_t ws_size,
                              hipStream_t stream) {
    const float* x   = (const float*)d_in[0];
    const float* eW1 = (const float*)d_in[1];
    const float* eb1 = (const float*)d_in[2];
    const float* eW2 = (const float*)d_in[3];
    const float* eb2 = (const float*)d_in[4];
    const float* eW3 = (const float*)d_in[5];
    const float* eb3 = (const float*)d_in[6];
    const float* gW1 = (const float*)d_in[7];
    const float* gb1 = (const float*)d_in[8];
    const float* gW2 = (const float*)d_in[9];
    const float* gb2 = (const float*)d_in[10];
    const float* gW3 = (const float*)d_in[11];
    const float* gb3 = (const float*)d_in[12];
    float* out = (float*)d_out;

    // 1-block pre-pack of gating weights (f16 RNE pairs), stream-ordered
    hipLaunchKernelGGL(pack_kernel, dim3(1), dim3(256), 0, stream, gW1, gW2, gW3);

    dim3 grid(BTOT / 256), block(256);
    hipLaunchKernelGGL(hybrid_ruc_kernel, grid, block, 0, stream,
                       x, eW1, eb1, eW2, eb2, eW3, eb3,
                       gW1, gb1, gW2, gb2, gW3, gb3, out);
}

// Round 11
// 241.396 us; speedup vs baseline: 1.1398x; 1.0464x over previous
//
#include <hip/hip_runtime.h>

#define BTOT 1048576
#define D 17
#define H 8
#define OUT 6
#define E 4
#define G1 64
#define G2 32
#define GTHR 1.0e-2f

typedef float f32x4 __attribute__((ext_vector_type(4)));
typedef float f32x2 __attribute__((ext_vector_type(2)));
typedef __fp16 h16x2 __attribute__((ext_vector_type(2)));
typedef __fp16 h16x8 __attribute__((ext_vector_type(8)));

union UH8 { h16x2 p[4]; h16x8 v; };

// 16x16x32 f16 MFMA, single term (f16 rel err 2^-11; logits pass harness at
// this precision -- proven R9 -- and argmax is protected by the exact fallback)
#define MMF(dacc, a, b) \
    dacc = __builtin_amdgcn_mfma_f32_16x16x32_f16(a, b, dacc, 0, 0, 0);

#define WSTR 296  // expert LDS stride (dwords): blocks start on bank groups {0,8,16,24}

__global__ __launch_bounds__(256, 2) void hybrid_ruc_kernel(
    const float* __restrict__ x,
    const float* __restrict__ eW1, const float* __restrict__ eb1,
    const float* __restrict__ eW2, const float* __restrict__ eb2,
    const float* __restrict__ eW3, const float* __restrict__ eb3,
    const float* __restrict__ gW1, const float* __restrict__ gb1,
    const float* __restrict__ gW2, const float* __restrict__ gb2,
    const float* __restrict__ gW3, const float* __restrict__ gb3,
    float* __restrict__ out)
{
    // ---- LDS: 17472 + 4736 + 16384 = 38592 B -> 4 blocks/CU ----
    __shared__ float sx[256 * D + 16];        // x rows + zero tail (A1 over-read)
    __shared__ __align__(16) float swl[E * WSTR];   // expert weights (R1 layout)
    __shared__ __align__(16) float sscr[4][1024];   // per-wave scratch (h1/h2/logits/fallback)

    const int tid = threadIdx.x;
    const int wv  = tid >> 6;
    const int ln  = tid & 63;
    const int g   = ln >> 4;   // k-block group for MFMA fragments
    const int nn  = ln & 15;   // row (A) / col (B,D) within 16-tile
    const long long bbase = (long long)blockIdx.x * 256;
    float* scr = sscr[wv];

    // ---- stage x rows (coalesced, R1/R9 pattern) + zero tail ----
    #pragma unroll
    for (int k = 0; k < D; ++k) {
        int t = tid + k * 256;
        sx[t] = x[bbase * D + t];
    }
    if (tid < 16) sx[256 * D + tid] = 0.0f;

    // ---- stage expert weights into LDS (R1 bank-group layout, proven) ----
    for (int t = tid; t < E * D * H; t += 256) {          // eW1: 544
        swl[(t / 136) * WSTR + (t % 136)] = eW1[t];
    }
    if (tid < E * H * H) {                                 // eW2: 256
        swl[(tid / 64) * WSTR + 144 + (tid % 64)] = eW2[tid];
    }
    if (tid < E * H * OUT) {                               // eW3: 192, rows padded to 8
        int e = tid / 48, r = tid % 48, k = r / 6, o = r % 6;
        swl[e * WSTR + 216 + k * 8 + o] = eW3[tid];
    }
    if (tid < E * H) swl[(tid / 8) * WSTR + 136 + (tid % 8)] = eb1[tid];
    if (tid < E * H) swl[(tid / 8) * WSTR + 208 + (tid % 8)] = eb2[tid];
    if (tid < E * OUT) swl[(tid / 6) * WSTR + 280 + (tid % 6)] = eb3[tid];

    // ---- hoist gating biases + f16 B-fragments from global (one-time) ----
    float cb1[4], cb2[2], cb3;
    #pragma unroll
    for (int ct = 0; ct < 4; ++ct) cb1[ct] = gb1[ct * 16 + nn];
    cb2[0] = gb2[nn]; cb2[1] = gb2[16 + nn];
    cb3 = (nn < 4) ? gb3[nn] : 0.0f;

    // B-frag layout (verified R4): lane(g,nn) element j = W^T[n][k=g*8+j]
    h16x8 B1f[4];                  // k>=17 and g==3 -> 0
    #pragma unroll
    for (int ct = 0; ct < 4; ++ct) {
        UH8 u;
        #pragma unroll
        for (int j = 0; j < 8; ++j) {
            const int k = g * 8 + j, n = ct * 16 + nn;
            u.v[j] = (__fp16)((k < D) ? gW1[k * G1 + n] : 0.0f);
        }
        B1f[ct] = u.v;
    }
    h16x8 B2f[2][2];               // k = kt*32 + g*8 + j (all valid)
    #pragma unroll
    for (int ct = 0; ct < 2; ++ct)
        #pragma unroll
        for (int kt = 0; kt < 2; ++kt) {
            UH8 u;
            #pragma unroll
            for (int j = 0; j < 8; ++j) {
                const int k = kt * 32 + g * 8 + j, n = ct * 16 + nn;
                u.v[j] = (__fp16)gW2[k * G2 + n];
            }
            B2f[ct][kt] = u.v;
        }
    h16x8 B3f;                     // cols nn>=4 zero
    {
        UH8 u;
        #pragma unroll
        for (int j = 0; j < 8; ++j) {
            const int k = g * 8 + j;
            u.v[j] = (__fp16)((nn < 4) ? gW3[k * E + nn] : 0.0f);
        }
        B3f = u.v;
    }
    __syncthreads();

    // ======== gating via f16 MFMA (per-wave: 4 row-tiles of 16 samples) ====
    f32x4 Lg[4];
    #pragma unroll
    for (int rt = 0; rt < 4; ++rt) {
        const int srow = wv * 64 + rt * 16 + nn;
        // A1 frag: x[srow][k=g*8..+7] as f16 (g==3 clamps: zero weights there)
        UH8 a1;
        {
            const int xb = srow * D + ((g == 3) ? 0 : g * 8);
            #pragma unroll
            for (int j2 = 0; j2 < 4; ++j2)
                a1.p[j2] = __builtin_amdgcn_cvt_pkrtz(sx[xb + 2 * j2], sx[xb + 2 * j2 + 1]);
        }

        // L1: 17->64, 4 col-tiles; relu + swizzled h1 write (R8-proven layout)
        #pragma unroll
        for (int ct = 0; ct < 4; ++ct) {
            f32x4 d = {cb1[ct], cb1[ct], cb1[ct], cb1[ct]};
            MMF(d, a1.v, B1f[ct]);
            #pragma unroll
            for (int r = 0; r < 4; ++r) {
                float hv = fmaxf(d[r], 0.0f);
                int s = g * 4 + r, n = ct * 16 + nn;
                scr[s * 64 + (((n >> 2) ^ (s & 15)) << 2) + (n & 3)] = hv;
            }
        }

        // A2 frags from h1 (swizzled b128 reads, R8-proven)
        UH8 a2[2];
        #pragma unroll
        for (int kt = 0; kt < 2; ++kt) {
            int kb0 = kt * 8 + g * 2;
            f32x4 va = *(const f32x4*)(&scr[nn * 64 + ((kb0 ^ nn) << 2)]);
            f32x4 vb = *(const f32x4*)(&scr[nn * 64 + (((kb0 + 1) ^ nn) << 2)]);
            a2[kt].p[0] = __builtin_amdgcn_cvt_pkrtz(va.x, va.y);
            a2[kt].p[1] = __builtin_amdgcn_cvt_pkrtz(va.z, va.w);
            a2[kt].p[2] = __builtin_amdgcn_cvt_pkrtz(vb.x, vb.y);
            a2[kt].p[3] = __builtin_amdgcn_cvt_pkrtz(vb.z, vb.w);
        }

        // L2: 64->32, 2 col-tiles x 2 k-tiles
        #pragma unroll
        for (int ct = 0; ct < 2; ++ct) {
            f32x4 d = {cb2[ct], cb2[ct], cb2[ct], cb2[ct]};
            MMF(d, a2[0].v, B2f[ct][0]);
            MMF(d, a2[1].v, B2f[ct][1]);
            #pragma unroll
            for (int r = 0; r < 4; ++r) {
                float hv = fmaxf(d[r], 0.0f);
                int s = g * 4 + r, n = ct * 16 + nn;
                scr[s * 32 + (((n >> 2) ^ (s & 7)) << 2) + (n & 3)] = hv;
            }
        }

        // A3 frag from h2 (R4-proven swizzle)
        UH8 a3;
        {
            f32x4 va = *(const f32x4*)(&scr[nn * 32 + (((2 * g) ^ (nn & 7)) << 2)]);
            f32x4 vb = *(const f32x4*)(&scr[nn * 32 + (((2 * g + 1) ^ (nn & 7)) << 2)]);
            a3.p[0] = __builtin_amdgcn_cvt_pkrtz(va.x, va.y);
            a3.p[1] = __builtin_amdgcn_cvt_pkrtz(va.z, va.w);
            a3.p[2] = __builtin_amdgcn_cvt_pkrtz(vb.x, vb.y);
            a3.p[3] = __builtin_amdgcn_cvt_pkrtz(vb.z, vb.w);
        }

        // L3: 32->4
        f32x4 d3 = {cb3, cb3, cb3, cb3};
        MMF(d3, a3.v, B3f);
        Lg[rt] = d3;
    }

    // ---- redistribute logits: D-layout -> one sample per lane (proven) ----
    if (nn < 4) {
        #pragma unroll
        for (int rt = 0; rt < 4; ++rt)
            #pragma unroll
            for (int r = 0; r < 4; ++r)
                scr[(rt * 16 + g * 4 + r) * 4 + nn] = Lg[rt][r];
    }
    f32x4 lgv = *(const f32x4*)(&scr[ln * 4]);

    // ---- argmax (first-max-wins) + top-2 gap ----
    int sel = 0;
    {
        float b = lgv.x;
        if (lgv.y > b) { b = lgv.y; sel = 1; }
        if (lgv.z > b) { b = lgv.z; sel = 2; }
        if (lgv.w > b) { b = lgv.w; sel = 3; }
    }
    float mx01 = fmaxf(lgv.x, lgv.y), mn01 = fminf(lgv.x, lgv.y);
    float mx23 = fmaxf(lgv.z, lgv.w), mn23 = fminf(lgv.z, lgv.w);
    float best   = fmaxf(mx01, mx23);
    float second = fmaxf(fminf(mx01, mx23), (mx01 >= mx23) ? mn01 : mn23);

    // ---- rare exact-fp32 cooperative fallback for near-tie routing ----
    unsigned long long fmask = __ballot(best - second < GTHR);
    if (fmask) {
        do {
            int sl = (int)__builtin_ctzll(fmask);
            fmask &= (fmask - 1);
            const int fr = wv * 64 + sl;           // flagged sample's sx row
            float h1j = gb1[ln];
            #pragma unroll 1
            for (int i = 0; i < D; ++i)
                h1j = __builtin_fmaf(sx[fr * D + i], gW1[i * G1 + ln], h1j);
            scr[ln] = fmaxf(h1j, 0.0f);
            int j2 = ln & 31;
            float h2j = gb2[j2];
            #pragma unroll 4
            for (int c2 = 0; c2 < G1; ++c2)
                h2j = __builtin_fmaf(scr[c2], gW2[c2 * G2 + j2], h2j);
            scr[64 + j2] = fmaxf(h2j, 0.0f);
            int e = ln & 3;
            float lge = gb3[e];
            #pragma unroll 4
            for (int jj = 0; jj < G2; ++jj)
                lge = __builtin_fmaf(scr[64 + jj], gW3[jj * E + e], lge);
            float l0 = __shfl(lge, 0), l1 = __shfl(lge, 1);
            float l2 = __shfl(lge, 2), l3 = __shfl(lge, 3);
            int s2 = 0; float bb = l0;
            if (l1 > bb) { bb = l1; s2 = 1; }
            if (l2 > bb) { bb = l2; s2 = 2; }
            if (l3 > bb) { bb = l3; s2 = 3; }
            if (ln == sl) sel = s2;
        } while (fmask);
    }

    // ---- selected expert only, fp32-exact, weights from LDS (R1-proven) ----
    float xr[D];
    #pragma unroll
    for (int i = 0; i < D; ++i) xr[i] = sx[tid * D + i];
    const float* wl = &swl[sel * WSTR];

    float t1[H];
    {
        f32x4 ba = *(const f32x4*)(wl + 136);
        f32x4 bb = *(const f32x4*)(wl + 140);
        t1[0]=ba.x; t1[1]=ba.y; t1[2]=ba.z; t1[3]=ba.w;
        t1[4]=bb.x; t1[5]=bb.y; t1[6]=bb.z; t1[7]=bb.w;
    }
    #pragma unroll
    for (int i = 0; i < D; ++i) {
        const float xi = xr[i];
        f32x4 wa = *(const f32x4*)(wl + i * 8);
        f32x4 wb = *(const f32x4*)(wl + i * 8 + 4);
        t1[0] = __builtin_fmaf(xi, wa.x, t1[0]);
        t1[1] = __builtin_fmaf(xi, wa.y, t1[1]);
        t1[2] = __builtin_fmaf(xi, wa.z, t1[2]);
        t1[3] = __builtin_fmaf(xi, wa.w, t1[3]);
        t1[4] = __builtin_fmaf(xi, wb.x, t1[4]);
        t1[5] = __builtin_fmaf(xi, wb.y, t1[5]);
        t1[6] = __builtin_fmaf(xi, wb.z, t1[6]);
        t1[7] = __builtin_fmaf(xi, wb.w, t1[7]);
    }
    float t2[H];
    {
        f32x4 ba = *(const f32x4*)(wl + 208);
        f32x4 bb = *(const f32x4*)(wl + 212);
        t2[0]=ba.x; t2[1]=ba.y; t2[2]=ba.z; t2[3]=ba.w;
        t2[4]=bb.x; t2[5]=bb.y; t2[6]=bb.z; t2[7]=bb.w;
    }
    #pragma unroll
    for (int k = 0; k < H; ++k) {
        const float tv = fmaxf(t1[k], 0.0f);
        f32x4 wa = *(const f32x4*)(wl + 144 + k * 8);
        f32x4 wb = *(const f32x4*)(wl + 144 + k * 8 + 4);
        t2[0] = __builtin_fmaf(tv, wa.x, t2[0]);
        t2[1] = __builtin_fmaf(tv, wa.y, t2[1]);
        t2[2] = __builtin_fmaf(tv, wa.z, t2[2]);
        t2[3] = __builtin_fmaf(tv, wa.w, t2[3]);
        t2[4] = __builtin_fmaf(tv, wb.x, t2[4]);
        t2[5] = __builtin_fmaf(tv, wb.y, t2[5]);
        t2[6] = __builtin_fmaf(tv, wb.z, t2[6]);
        t2[7] = __builtin_fmaf(tv, wb.w, t2[7]);
    }
    float pred[OUT];
    {
        f32x4 ba = *(const f32x4*)(wl + 280);
        pred[0]=ba.x; pred[1]=ba.y; pred[2]=ba.z; pred[3]=ba.w;
        pred[4]=wl[284]; pred[5]=wl[285];
    }
    #pragma unroll
    for (int k = 0; k < H; ++k) {
        const float tv = fmaxf(t2[k], 0.0f);
        f32x4 wa = *(const f32x4*)(wl + 216 + k * 8);
        f32x2 wb = *(const f32x2*)(wl + 216 + k * 8 + 4);
        pred[0] = __builtin_fmaf(tv, wa.x, pred[0]);
        pred[1] = __builtin_fmaf(tv, wa.y, pred[1]);
        pred[2] = __builtin_fmaf(tv, wa.z, pred[2]);
        pred[3] = __builtin_fmaf(tv, wa.w, pred[3]);
        pred[4] = __builtin_fmaf(tv, wb.x, pred[4]);
        pred[5] = __builtin_fmaf(tv, wb.y, pred[5]);
    }

    // ---- stores: predictions [B,6] then gating_logits [B,4] ----
    const long long b = bbase + tid;
    f32x2 p0 = {pred[0], pred[1]};
    f32x2 p1 = {pred[2], pred[3]};
    f32x2 p2 = {pred[4], pred[5]};
    *(f32x2*)(out + b * 6)     = p0;
    *(f32x2*)(out + b * 6 + 2) = p1;
    *(f32x2*)(out + b * 6 + 4) = p2;
    float* lout = out + (long long)BTOT * OUT;
    *(f32x4*)(lout + b * 4) = lgv;
}

extern "C" void kernel_launch(void* const* d_in, const int* in_sizes, int n_in,
                              void* d_out, int out_size, void* d_ws, size_t ws_size,
                              hipStream_t stream) {
    const float* x   = (const float*)d_in[0];
    const float* eW1 = (const float*)d_in[1];
    const float* eb1 = (const float*)d_in[2];
    const float* eW2 = (const float*)d_in[3];
    const float* eb2 = (const float*)d_in[4];
    const float* eW3 = (const float*)d_in[5];
    const float* eb3 = (const float*)d_in[6];
    const float* gW1 = (const float*)d_in[7];
    const float* gb1 = (const float*)d_in[8];
    const float* gW2 = (const float*)d_in[9];
    const float* gb2 = (const float*)d_in[10];
    const float* gW3 = (const float*)d_in[11];
    const float* gb3 = (const float*)d_in[12];
    float* out = (float*)d_out;

    dim3 grid(BTOT / 256), block(256);
    hipLaunchKernelGGL(hybrid_ruc_kernel, grid, block, 0, stream,
                       x, eW1, eb1, eW2, eb2, eW3, eb3,
                       gW1, gb1, gW2, gb2, gW3, gb3, out);
}